// Round 4
// baseline (3172.343 us; speedup 1.0000x reference)
//
#include <hip/hip_runtime.h>
#include <math.h>
#include <stdint.h>

#define BB 32
#define TT 2048
#define FF 128
#define HH 512
#define FCC 128
#define QW 8
#define NTH 640   // 10 waves: 0-7 compute+add, 8 reader, 9 scorer (WG q==0 only)

#define SCALE_F     4194304.0f             // 2^22 fixed-point scale (i32-decodable)
#define INV_SCALE_F (1.0f/4194304.0f)
#define CNT_ONE     (1ull<<48)             // arrival counter increment
#define BIAS_TOTAL  (1ll<<46)              // keeps low field positive: no carry into bit 48
#define BIAS_SHARE  (1ll<<43)              // BIAS_TOTAL / 8 (one share per WG, first use of each parity)
// 2^46 and 2^43 are both ≡ 0 mod 2^32, and |A·2^22| < 2^31, so the reader
// decodes the signed sum as (int32)(low 32 bits) — no 64-bit ops needed.

typedef float f32x2 __attribute__((ext_vector_type(2)));

__global__ void ws_zero(uint64_t* g) {     // counters/tags must start at 0 (0xAA poison aliases)
    g[(size_t)blockIdx.x * blockDim.x + threadIdx.x] = 0ull;
}

__device__ __forceinline__ void wait_lgkm0() {
    asm volatile("s_waitcnt lgkmcnt(0)" ::: "memory");
}

__device__ __forceinline__ float fast_tanh(float z) {
    float ax = fabsf(z);
    float e  = __expf(-2.0f * ax);
    float r  = (1.0f - e) / (1.0f + e);
    return copysignf(r, z);
}

// packed f32 FMA: d.lo += a.lo*b.lo, d.hi += a.hi*b.hi  (full-rate on CDNA4)
__device__ __forceinline__ void pk_fma(f32x2& d, f32x2 a, f32x2 b) {
    asm("v_pk_fma_f32 %0, %1, %2, %0" : "+v"(d) : "v"(a), "v"(b));
}
__device__ __forceinline__ f32x2 lo2(float4 v) { f32x2 r; r.x = v.x; r.y = v.y; return r; }
__device__ __forceinline__ f32x2 hi2(float4 v) { f32x2 r; r.x = v.z; r.y = v.w; return r; }

__device__ __forceinline__ uint64_t gld_agent(const uint64_t* p) {
    return __hip_atomic_load(p, __ATOMIC_RELAXED, __HIP_MEMORY_SCOPE_AGENT);
}
__device__ __forceinline__ int flag_ld(const int* p) {
    return __hip_atomic_load(p, __ATOMIC_RELAXED, __HIP_MEMORY_SCOPE_WORKGROUP);
}

// IC-gather RNN. grid=256 (1 WG/CU), b=blk>>3, q=blk&7.
// Transposed ownership: WG q owns COLS [q*64,q*64+64) of W_hh (+ cols
// [q*16..+16) of W_ih/x) for ALL 512 rows. Per step i:
//   waves 0-7 (thread row r=w*64+lane): x-part FIRST (no h dep, hides under
//     flag wait), 2-deep LDS flag poll, then packed-FMA
//     partial A = W_hh[r][own cols]·h + W_ih[r][own xcols]·x_i, i32 fixed-point
//     delta vs same-parity 2 steps ago, ONE fire-and-forget
//     global_atomic_add((cnt=1)<<48 | delta) to slot[(i+1)&1][b][r].
//   wave 8 (prio 1): depth-4 rotating poll of OWN 64 slots, WAVE-UNIFORM
//     __all exits (no divergent-exec register games — R1/R2 lesson; VMEM
//     returns in-order so WAW on rotation regs is safe, compiler inserts
//     counted vmcnt waits from the visible data deps). Counter cannot pass
//     target until this wave publishes flag, so re-loads after ready are
//     benign. Decodes via (int32)low32, +bias, tanh, writes LDS h
//     (2-parity) + flag.
//   wave 7 extra: publishes chunk-dot of h_i (tagged u64) into 16-deep ring;
//     wave 9 (WG q==0) consumes ring, counts score>0, writes out[b].
// Parity-slot reuse safe: adds for use n+1 of buf P happen only after every
// WG read use n (read->flag->compute->add causality). Carry-safe u64 packing:
// low field = 2^46 + S_i*2^22, |S|<2^9 -> field in [2^46-2^31, 2^46+2^31],
// never crosses 0 or 2^48.
__global__ __launch_bounds__(NTH, 1)
void rnn_seq(const float* __restrict__ x, const int* __restrict__ lengths,
             const float* __restrict__ W_ih, const float* __restrict__ W_hh,
             const float* __restrict__ b_ih, const float* __restrict__ b_hh,
             const float* __restrict__ W1, const float* __restrict__ b1,
             const float* __restrict__ W2, const float* __restrict__ b2,
             float* __restrict__ out, uint64_t* __restrict__ ws)
{
    const int blk  = blockIdx.x;
    const int b    = blk >> 3;      // batch (spread mapping)
    const int q    = blk & 7;       // col-chunk owned by this WG
    const int tid  = threadIdx.x;
    const int w    = tid >> 6;
    const int lane = tid & 63;
    const int len  = lengths[b];

    uint64_t* gh  = ws;                         // [2][BB][HH] row accumulators
    uint64_t* gsd = ws + 2 * BB * HH;           // [BB][16][8] scorer ring

    __shared__ float hsh[2][64];                // h chunk, 2-parity
    __shared__ float biass[64];
    __shared__ int   flag_s;                    // highest j with h_j in hsh[j&1]

    if (w == 8) {
        biass[lane] = b_ih[q * 64 + lane] + b_hh[q * 64 + lane];
        hsh[0][lane] = 0.0f;                    // h_0 = 0
        if (lane == 0) flag_s = 0;
    }
    __syncthreads();

    if (w < 8) {
        // ================= compute+add role: row r =================
        const int r = w * 64 + lane;
        float4 ww[16];
        { const float4* p = (const float4*)(W_hh + (size_t)r * HH + q * 64);
          #pragma unroll
          for (int k = 0; k < 16; ++k) ww[k] = p[k]; }
        float4 wi[4];
        { const float4* p = (const float4*)(W_ih + r * FF + q * 16);
          #pragma unroll
          for (int k = 0; k < 4; ++k) wi[k] = p[k]; }
        float wvreg = 0.0f;
        if (w == 7) {                           // scorer weight for col q*64+lane
            const int col = q * 64 + lane;
            #pragma unroll 8
            for (int f = 0; f < FCC; ++f) wvreg += W2[f] * W1[f * HH + col];
        }
        int prevI[2] = {0, 0};
        const float* xb = x + (size_t)b * TT * FF + q * 16;
        float4 xc[4], xn[4];
        { const float4* p = (const float4*)xb;
          #pragma unroll
          for (int k = 0; k < 4; ++k) xc[k] = p[k]; }
        { const float4* p = (const float4*)(xb + FF);
          #pragma unroll
          for (int k = 0; k < 4; ++k) xn[k] = p[k]; }

        uint64_t* ghb = gh + (size_t)b * HH + r;

        for (int i = 0; i < len; ++i) {
            // ---- x-part first: independent of h, hides under the flag wait
            f32x2 acc01 = {0.0f, 0.0f};
            f32x2 acc23 = {0.0f, 0.0f};
            #pragma unroll
            for (int k = 0; k < 4; ++k) {
                pk_fma(acc01, lo2(wi[k]), lo2(xc[k]));
                pk_fma(acc23, hi2(wi[k]), hi2(xc[k]));
            }

            // 2-deep LDS flag poll (flag_s is wave-uniform -> uniform loop)
            {
                int f0 = flag_ld(&flag_s);
                int f1 = flag_ld(&flag_s);
                for (;;) {
                    if (f0 >= i) break;
                    f0 = flag_ld(&flag_s);
                    if (f1 >= i) break;
                    f1 = flag_ld(&flag_s);
                }
            }
            const float* hc = hsh[i & 1];
            const float4* hq = (const float4*)hc;
            #pragma unroll
            for (int k = 0; k < 16; ++k) {
                float4 hk = hq[k];
                pk_fma(acc01, lo2(ww[k]), lo2(hk));
                pk_fma(acc23, hi2(ww[k]), hi2(hk));
            }
            float A = (acc01.x + acc01.y) + (acc23.x + acc23.y);

            float hown = 0.0f;
            if (w == 7) hown = hc[lane];        // capture h_i before add (dep-ordered by publish)

            int fi = __float2int_rn(A * SCALE_F);
            const int pn = (i + 1) & 1;
            long long con = (long long)CNT_ONE + (long long)(fi - prevI[pn])
                          + ((i < 2) ? BIAS_SHARE : 0);
            prevI[pn] = fi;
            atomicAdd((unsigned long long*)(ghb + (size_t)pn * BB * HH),
                      (unsigned long long)con);          // fire-and-forget RMW

            if (w == 7 && i > 0) {              // scorer chunk-dot of h_i
                float d = hown * wvreg;
                d += __shfl_xor(d, 1);  d += __shfl_xor(d, 2);
                d += __shfl_xor(d, 4);  d += __shfl_xor(d, 8);
                d += __shfl_xor(d, 16); d += __shfl_xor(d, 32);
                if (lane == 0) {
                    uint64_t pk = ((uint64_t)(uint32_t)i << 32) |
                                  (uint64_t)__float_as_uint(d);
                    __hip_atomic_store(&gsd[((size_t)b * 16 + (i & 15)) * 8 + q],
                                       pk, __ATOMIC_RELAXED, __HIP_MEMORY_SCOPE_AGENT);
                }
            }
            #pragma unroll
            for (int k = 0; k < 4; ++k) xc[k] = xn[k];
            if (i + 2 < len) {
                const float4* p = (const float4*)(xb + (size_t)(i + 2) * FF);
                #pragma unroll
                for (int k = 0; k < 4; ++k) xn[k] = p[k];
            }
        }
        if (w == 7) {                            // final scorer dot: h_len
            while (flag_ld(&flag_s) < len) {}
            float d = hsh[len & 1][lane] * wvreg;
            d += __shfl_xor(d, 1);  d += __shfl_xor(d, 2);
            d += __shfl_xor(d, 4);  d += __shfl_xor(d, 8);
            d += __shfl_xor(d, 16); d += __shfl_xor(d, 32);
            if (lane == 0) {
                uint64_t pk = ((uint64_t)(uint32_t)len << 32) |
                              (uint64_t)__float_as_uint(d);
                __hip_atomic_store(&gsd[((size_t)b * 16 + (len & 15)) * 8 + q],
                                   pk, __ATOMIC_RELAXED, __HIP_MEMORY_SCOPE_AGENT);
            }
        }
    } else if (w == 8) {
        // ================= reader role: own 64 slots =================
        __builtin_amdgcn_s_setprio(1);          // win SIMD arbitration vs spinning compute waves
        float hval = 0.0f;
        for (int i = 0; i < len; ++i) {
            const int j  = i + 1;
            const int pn = j & 1;
            const uint64_t target = 8ull * (uint64_t)((j + 1) >> 1); // 8*uses of this parity
            uint64_t* pr = gh + (size_t)pn * BB * HH + (size_t)b * HH + q * 64 + lane;
            // depth-4 rotating poll, wave-uniform __all exits. Sampling
            // interval ~RT/4 instead of RT. Re-loads after a lane is ready
            // are benign (counter is final until we publish flag below).
            uint64_t u;
            uint64_t u0 = gld_agent(pr);
            uint64_t u1 = gld_agent(pr);
            uint64_t u2 = gld_agent(pr);
            uint64_t u3 = gld_agent(pr);
            for (;;) {
                if (__all((u0 >> 48) == target)) { u = u0; break; }
                u0 = gld_agent(pr);
                if (__all((u1 >> 48) == target)) { u = u1; break; }
                u1 = gld_agent(pr);
                if (__all((u2 >> 48) == target)) { u = u2; break; }
                u2 = gld_agent(pr);
                if (__all((u3 >> 48) == target)) { u = u3; break; }
                u3 = gld_agent(pr);
            }
            // i32 decode: 2^46/2^43 bias ≡ 0 mod 2^32, |S·2^22| < 2^31
            float pre = (float)(int)(uint32_t)u * INV_SCALE_F + biass[lane];
            hval = fast_tanh(pre);
            hsh[pn][lane] = hval;
            wait_lgkm0();
            if (lane == 0)
                __hip_atomic_store(&flag_s, j, __ATOMIC_RELAXED,
                                   __HIP_MEMORY_SCOPE_WORKGROUP);
        }
        out[BB + b * HH + q * 64 + lane] = hval;   // h_final chunk
    } else {
        // ================= scorer consumer (WG q==0 only) =================
        if (q != 0) return;
        float cconst = b2[0];
        for (int f = 0; f < FCC; ++f) cconst += W2[f] * b1[f];
        int count = 0;
        for (int j = 1; j <= len; ++j) {
            float d = 0.0f;
            if (lane < 8) {
                uint64_t* pr = gsd + ((size_t)b * 16 + (j & 15)) * 8 + lane;
                uint64_t u;
                do { u = gld_agent(pr); }
                while ((int)(u >> 32) != j);
                d = __uint_as_float((uint32_t)u);
            }
            d += __shfl_xor(d, 1); d += __shfl_xor(d, 2); d += __shfl_xor(d, 4);
            if (lane == 0 && d + cconst > 0.0f) ++count;
        }
        if (lane == 0) out[b] = (float)count;
    }
}

extern "C" void kernel_launch(void* const* d_in, const int* in_sizes, int n_in,
                              void* d_out, int out_size, void* d_ws, size_t ws_size,
                              hipStream_t stream) {
    const float* x    = (const float*)d_in[0];
    const int*   lens = (const int*)d_in[1];
    const float* W_ih = (const float*)d_in[2];
    const float* W_hh = (const float*)d_in[3];
    const float* b_ih = (const float*)d_in[4];
    const float* b_hh = (const float*)d_in[5];
    const float* W1   = (const float*)d_in[6];
    const float* b1   = (const float*)d_in[7];
    const float* W2   = (const float*)d_in[8];
    const float* b2   = (const float*)d_in[9];
    float* out = (float*)d_out;
    uint64_t* ws = (uint64_t*)d_ws;   // 2*32*512 + 32*16*8 = 36864 u64 = 288 KB

    ws_zero<<<dim3(144), dim3(256), 0, stream>>>(ws);
    rnn_seq<<<dim3(BB * QW), dim3(NTH), 0, stream>>>(
        x, lens, W_ih, W_hh, b_ih, b_hh, W1, b1, W2, b2, out, ws);
}

// Round 5
// 2766.560 us; speedup vs baseline: 1.1467x; 1.1467x over previous
//
#include <hip/hip_runtime.h>
#include <math.h>
#include <stdint.h>

#define BB 32
#define TT 2048
#define FF 128
#define HH 512
#define FCC 128
#define QW 8
#define NTH 640   // 10 waves: 0-7 compute+add, 8 reader, 9 scorer (WG q==0 only)

#define SCALE_F     4194304.0f             // 2^22 fixed-point scale (i32-decodable)
#define INV_SCALE_F (1.0f/4194304.0f)
#define CNT_ONE     (1ull<<48)             // arrival counter increment
#define BIAS_TOTAL  (1ll<<46)              // keeps low field positive: no carry into bit 48
#define BIAS_SHARE  (1ll<<43)              // BIAS_TOTAL / 8 (one share per WG, first use of each parity)
// 2^46 and 2^43 are both ≡ 0 mod 2^32, and |A·2^22| < 2^31, so the reader
// decodes the signed sum as (int32)(low 32 bits) — no 64-bit ops needed.

#define WS_U64 (2*BB*HH + BB*16*8 + BB)    // gh + gsd + gx handshake

typedef float f32x2 __attribute__((ext_vector_type(2)));

__global__ void ws_zero(uint64_t* g) {     // counters/tags must start at 0 (0xAA poison aliases)
    size_t i = (size_t)blockIdx.x * blockDim.x + threadIdx.x;
    if (i < WS_U64) g[i] = 0ull;
}

__device__ __forceinline__ void wait_lgkm0() {
    asm volatile("s_waitcnt lgkmcnt(0)" ::: "memory");
}

__device__ __forceinline__ float fast_tanh(float z) {
    float ax = fabsf(z);
    float e  = __expf(-2.0f * ax);
    float r  = (1.0f - e) / (1.0f + e);
    return copysignf(r, z);
}

// packed f32 FMA: d.lo += a.lo*b.lo, d.hi += a.hi*b.hi  (full-rate on CDNA4)
__device__ __forceinline__ void pk_fma(f32x2& d, f32x2 a, f32x2 b) {
    asm("v_pk_fma_f32 %0, %1, %2, %0" : "+v"(d) : "v"(a), "v"(b));
}
__device__ __forceinline__ f32x2 lo2(float4 v) { f32x2 r; r.x = v.x; r.y = v.y; return r; }
__device__ __forceinline__ f32x2 hi2(float4 v) { f32x2 r; r.x = v.z; r.y = v.w; return r; }

__device__ __forceinline__ uint64_t gld_agent(const uint64_t* p) {
    return __hip_atomic_load(p, __ATOMIC_RELAXED, __HIP_MEMORY_SCOPE_AGENT);
}
__device__ __forceinline__ int flag_ld(const int* p) {
    return __hip_atomic_load(p, __ATOMIC_RELAXED, __HIP_MEMORY_SCOPE_WORKGROUP);
}

// IC-gather RNN. grid=256 (1 WG/CU). XCD-local mapping: b=blk&31, q=blk>>5
// puts all 8 WGs of batch b at blk ≡ b (mod 8) -> same XCD under round-robin
// dispatch. A startup handshake VERIFIES this (correctness never assumes it):
// each WG's wave8 reads HW_REG_XCC_ID, atomic-adds 1<<(8*xcc) into gx[b],
// waits byte-sum==8; local_ok iff all 8 arrivals in its OWN byte (exact
// consensus: all-in-one-byte => every member's xcc is that byte). If ok,
// the h-accumulator protocol runs with WORKGROUP-scope atomics: RMWs execute
// at the shared per-XCD L2 (no sc1; atomics never execute in L1) -> RT ~200cy
// instead of LLC ~600cy on BOTH the add flight and the reader poll. Reader
// polls via fetch_add of an asm-laundered zero (defeats LLVM's idempotent-
// rmw->atomic-load rewrite, which could hit stale L1). Fallback: agent scope
// everywhere (R3-verified behavior).
// Per step i: waves 0-7 (row r=w*64+lane): x-part first (hides under flag
// wait), LDS flag spin, packed-FMA partial A over own 64 cols, i32 fixed-
// point delta vs same-parity 2 steps ago, ONE fire-and-forget
// atomic_add((1<<48)|delta) to slot[(i+1)&1][b][r]. Wave 8 (prio 1): single-
// outstanding poll (R4: deeper polling delays the producers' RMWs on the
// same lines), decode (int32)low32, +bias, tanh, LDS h (2-parity) + flag.
// Wave 7 publishes chunk-dot to agent-scope ring; wave 9 (q==0) consumes.
// Parity-slot reuse safe (read->flag->compute->add causality). Carry-safe
// packing: low field = 2^46 + S*2^22, |S|<2^9.
__global__ __launch_bounds__(NTH, 1)
void rnn_seq(const float* __restrict__ x, const int* __restrict__ lengths,
             const float* __restrict__ W_ih, const float* __restrict__ W_hh,
             const float* __restrict__ b_ih, const float* __restrict__ b_hh,
             const float* __restrict__ W1, const float* __restrict__ b1,
             const float* __restrict__ W2, const float* __restrict__ b2,
             float* __restrict__ out, uint64_t* __restrict__ ws)
{
    const int blk  = blockIdx.x;
    const int b    = blk & 31;      // batch: all 8 WGs of b share blk%8 -> same XCD
    const int q    = blk >> 5;      // col-chunk owned by this WG
    const int tid  = threadIdx.x;
    const int w    = tid >> 6;
    const int lane = tid & 63;
    const int len  = lengths[b];

    uint64_t* gh  = ws;                         // [2][BB][HH] row accumulators
    uint64_t* gsd = ws + 2 * BB * HH;           // [BB][16][8] scorer ring
    uint64_t* gx  = gsd + BB * 16 * 8;          // [BB] xcd handshake

    __shared__ float hsh[2][64];                // h chunk, 2-parity
    __shared__ float biass[64];
    __shared__ int   flag_s;                    // highest j with h_j in hsh[j&1]
    __shared__ int   lok_s;                     // 1 = all 8 WGs on this XCD

    if (w == 8) {
        biass[lane] = b_ih[q * 64 + lane] + b_hh[q * 64 + lane];
        hsh[0][lane] = 0.0f;                    // h_0 = 0
        uint32_t xcc_raw;
        asm volatile("s_getreg_b32 %0, hwreg(HW_REG_XCC_ID)" : "=s"(xcc_raw));
        const uint32_t xcc = xcc_raw & 7;
        if (lane == 0) {
            flag_s = 0;
            uint64_t* gxp = gx + b;
            __hip_atomic_fetch_add(gxp, 1ull << (8 * xcc),
                                   __ATOMIC_RELAXED, __HIP_MEMORY_SCOPE_AGENT);
            uint64_t v;
            do { v = gld_agent(gxp); }
            while ((uint8_t)((v * 0x0101010101010101ull) >> 56) != 8);
            lok_s = (v == (8ull << (8 * xcc))) ? 1 : 0;
        }
    }
    __syncthreads();
    const bool lok = (lok_s != 0);

    if (w < 8) {
        // ================= compute+add role: row r =================
        const int r = w * 64 + lane;
        float4 ww[16];
        { const float4* p = (const float4*)(W_hh + (size_t)r * HH + q * 64);
          #pragma unroll
          for (int k = 0; k < 16; ++k) ww[k] = p[k]; }
        float4 wi[4];
        { const float4* p = (const float4*)(W_ih + r * FF + q * 16);
          #pragma unroll
          for (int k = 0; k < 4; ++k) wi[k] = p[k]; }
        float wvreg = 0.0f;
        if (w == 7) {                           // scorer weight for col q*64+lane
            const int col = q * 64 + lane;
            #pragma unroll 8
            for (int f = 0; f < FCC; ++f) wvreg += W2[f] * W1[f * HH + col];
        }
        int prevI[2] = {0, 0};
        const float* xb = x + (size_t)b * TT * FF + q * 16;
        float4 xc[4], xn[4];
        { const float4* p = (const float4*)xb;
          #pragma unroll
          for (int k = 0; k < 4; ++k) xc[k] = p[k]; }
        { const float4* p = (const float4*)(xb + FF);
          #pragma unroll
          for (int k = 0; k < 4; ++k) xn[k] = p[k]; }

        uint64_t* ghb = gh + (size_t)b * HH + r;

        for (int i = 0; i < len; ++i) {
            // ---- x-part first: independent of h, hides under the flag wait
            f32x2 acc01 = {0.0f, 0.0f};
            f32x2 acc23 = {0.0f, 0.0f};
            #pragma unroll
            for (int k = 0; k < 4; ++k) {
                pk_fma(acc01, lo2(wi[k]), lo2(xc[k]));
                pk_fma(acc23, hi2(wi[k]), hi2(xc[k]));
            }

            while (flag_ld(&flag_s) < i) {}
            const float* hc = hsh[i & 1];
            const float4* hq = (const float4*)hc;
            #pragma unroll
            for (int k = 0; k < 16; ++k) {
                float4 hk = hq[k];
                pk_fma(acc01, lo2(ww[k]), lo2(hk));
                pk_fma(acc23, hi2(ww[k]), hi2(hk));
            }
            float A = (acc01.x + acc01.y) + (acc23.x + acc23.y);

            float hown = 0.0f;
            if (w == 7) hown = hc[lane];        // capture h_i before add (dep-ordered by publish)

            int fi = __float2int_rn(A * SCALE_F);
            const int pn = (i + 1) & 1;
            long long con = (long long)CNT_ONE + (long long)(fi - prevI[pn])
                          + ((i < 2) ? BIAS_SHARE : 0);
            prevI[pn] = fi;
            uint64_t* slot = ghb + (size_t)pn * BB * HH;
            if (lok)                             // L2-local RMW (same-XCD verified)
                __hip_atomic_fetch_add(slot, (uint64_t)con,
                                       __ATOMIC_RELAXED, __HIP_MEMORY_SCOPE_WORKGROUP);
            else
                atomicAdd((unsigned long long*)slot, (unsigned long long)con);

            if (w == 7 && i > 0) {              // scorer chunk-dot of h_i
                float d = hown * wvreg;
                d += __shfl_xor(d, 1);  d += __shfl_xor(d, 2);
                d += __shfl_xor(d, 4);  d += __shfl_xor(d, 8);
                d += __shfl_xor(d, 16); d += __shfl_xor(d, 32);
                if (lane == 0) {
                    uint64_t pk = ((uint64_t)(uint32_t)i << 32) |
                                  (uint64_t)__float_as_uint(d);
                    __hip_atomic_store(&gsd[((size_t)b * 16 + (i & 15)) * 8 + q],
                                       pk, __ATOMIC_RELAXED, __HIP_MEMORY_SCOPE_AGENT);
                }
            }
            #pragma unroll
            for (int k = 0; k < 4; ++k) xc[k] = xn[k];
            if (i + 2 < len) {
                const float4* p = (const float4*)(xb + (size_t)(i + 2) * FF);
                #pragma unroll
                for (int k = 0; k < 4; ++k) xn[k] = p[k];
            }
        }
        if (w == 7) {                            // final scorer dot: h_len
            while (flag_ld(&flag_s) < len) {}
            float d = hsh[len & 1][lane] * wvreg;
            d += __shfl_xor(d, 1);  d += __shfl_xor(d, 2);
            d += __shfl_xor(d, 4);  d += __shfl_xor(d, 8);
            d += __shfl_xor(d, 16); d += __shfl_xor(d, 32);
            if (lane == 0) {
                uint64_t pk = ((uint64_t)(uint32_t)len << 32) |
                              (uint64_t)__float_as_uint(d);
                __hip_atomic_store(&gsd[((size_t)b * 16 + (len & 15)) * 8 + q],
                                   pk, __ATOMIC_RELAXED, __HIP_MEMORY_SCOPE_AGENT);
            }
        }
    } else if (w == 8) {
        // ================= reader role: own 64 slots =================
        __builtin_amdgcn_s_setprio(1);          // win SIMD arbitration vs spinning compute waves
        uint64_t z = 0;
        asm("" : "+v"(z));                      // opaque zero: keeps fetch_add a real RMW
        float hval = 0.0f;
        for (int i = 0; i < len; ++i) {
            const int j  = i + 1;
            const int pn = j & 1;
            const uint64_t target = 8ull * (uint64_t)((j + 1) >> 1); // 8*uses of this parity
            uint64_t* pr = gh + (size_t)pn * BB * HH + (size_t)b * HH + q * 64 + lane;
            uint64_t u;
            if (lok) {
                // workgroup-scope RMW(+0): executes at the XCD L2 (atomics
                // bypass L1), returns the fresh value. Single-outstanding.
                do { u = __hip_atomic_fetch_add(pr, z, __ATOMIC_RELAXED,
                                                __HIP_MEMORY_SCOPE_WORKGROUP); }
                while ((u >> 48) != target);
            } else {
                do { u = gld_agent(pr); } while ((u >> 48) != target);
            }
            // i32 decode: 2^46/2^43 bias ≡ 0 mod 2^32, |S·2^22| < 2^31
            float pre = (float)(int)(uint32_t)u * INV_SCALE_F + biass[lane];
            hval = fast_tanh(pre);
            hsh[pn][lane] = hval;
            wait_lgkm0();
            if (lane == 0)
                __hip_atomic_store(&flag_s, j, __ATOMIC_RELAXED,
                                   __HIP_MEMORY_SCOPE_WORKGROUP);
        }
        out[BB + b * HH + q * 64 + lane] = hval;   // h_final chunk
    } else {
        // ================= scorer consumer (WG q==0 only) =================
        if (q != 0) return;
        float cconst = b2[0];
        for (int f = 0; f < FCC; ++f) cconst += W2[f] * b1[f];
        int count = 0;
        for (int j = 1; j <= len; ++j) {
            float d = 0.0f;
            if (lane < 8) {
                uint64_t* pr = gsd + ((size_t)b * 16 + (j & 15)) * 8 + lane;
                uint64_t u;
                do { u = gld_agent(pr); }
                while ((int)(u >> 32) != j);
                d = __uint_as_float((uint32_t)u);
            }
            d += __shfl_xor(d, 1); d += __shfl_xor(d, 2); d += __shfl_xor(d, 4);
            if (lane == 0 && d + cconst > 0.0f) ++count;
        }
        if (lane == 0) out[b] = (float)count;
    }
}

extern "C" void kernel_launch(void* const* d_in, const int* in_sizes, int n_in,
                              void* d_out, int out_size, void* d_ws, size_t ws_size,
                              hipStream_t stream) {
    const float* x    = (const float*)d_in[0];
    const int*   lens = (const int*)d_in[1];
    const float* W_ih = (const float*)d_in[2];
    const float* W_hh = (const float*)d_in[3];
    const float* b_ih = (const float*)d_in[4];
    const float* b_hh = (const float*)d_in[5];
    const float* W1   = (const float*)d_in[6];
    const float* b1   = (const float*)d_in[7];
    const float* W2   = (const float*)d_in[8];
    const float* b2   = (const float*)d_in[9];
    float* out = (float*)d_out;
    uint64_t* ws = (uint64_t*)d_ws;   // WS_U64 u64 = 295168 B

    ws_zero<<<dim3(145), dim3(256), 0, stream>>>(ws);
    rnn_seq<<<dim3(BB * QW), dim3(NTH), 0, stream>>>(
        x, lens, W_ih, W_hh, b_ih, b_hh, W1, b1, W2, b2, out, ws);
}

// Round 7
// 2666.000 us; speedup vs baseline: 1.1899x; 1.0377x over previous
//
#include <hip/hip_runtime.h>
#include <math.h>
#include <stdint.h>

#define BB 32
#define TT 2048
#define FF 128
#define HH 512
#define FCC 128
#define QW 8
#define NTH 640   // 10 waves: 0-7 compute+add, 8 reader, 9 scorer (q==0) / barrier-idle

#define SCALE_F     4194304.0f             // 2^22 fixed-point scale (i32-decodable)
#define INV_SCALE_F (1.0f/4194304.0f)
#define CNT_ONE     (1ull<<48)             // arrival counter increment
#define BIAS_TOTAL  (1ll<<46)              // keeps low field positive: no carry into bit 48
#define BIAS_SHARE  (1ll<<43)              // BIAS_TOTAL / 8 (one share per WG, first use of each parity)
// 2^46 and 2^43 are both ≡ 0 mod 2^32, and |A·2^22| < 2^31, so the reader
// decodes the signed sum as (int32)(low 32 bits) — no 64-bit ops needed.

#define WS_U64 (2*BB*HH + BB*16*8 + BB)    // gh + gsd + gx handshake

typedef float f32x2 __attribute__((ext_vector_type(2)));

__global__ void ws_zero(uint64_t* g) {     // counters/tags must start at 0 (0xAA poison aliases)
    size_t i = (size_t)blockIdx.x * blockDim.x + threadIdx.x;
    if (i < WS_U64) g[i] = 0ull;
}

__device__ __forceinline__ void wait_lgkm0() {
    asm volatile("s_waitcnt lgkmcnt(0)" ::: "memory");
}

// raw WG barrier: NO implicit vmcnt drain (fire-and-forget adds stay in
// flight). Compile-level memory fences on both sides so LDS ops can't be
// scheduled across it.
__device__ __forceinline__ void wg_barrier() {
    asm volatile("" ::: "memory");
    __builtin_amdgcn_s_barrier();
    asm volatile("" ::: "memory");
}

__device__ __forceinline__ float fast_tanh(float z) {
    float ax = fabsf(z);
    float e  = __expf(-2.0f * ax);
    float r  = (1.0f - e) / (1.0f + e);
    return copysignf(r, z);
}

// packed f32 FMA: d.lo += a.lo*b.lo, d.hi += a.hi*b.hi  (full-rate on CDNA4)
__device__ __forceinline__ void pk_fma(f32x2& d, f32x2 a, f32x2 b) {
    asm("v_pk_fma_f32 %0, %1, %2, %0" : "+v"(d) : "v"(a), "v"(b));
}
__device__ __forceinline__ f32x2 lo2(float4 v) { f32x2 r; r.x = v.x; r.y = v.y; return r; }
__device__ __forceinline__ f32x2 hi2(float4 v) { f32x2 r; r.x = v.z; r.y = v.w; return r; }

__device__ __forceinline__ uint64_t gld_agent(const uint64_t* p) {
    return __hip_atomic_load(p, __ATOMIC_RELAXED, __HIP_MEMORY_SCOPE_AGENT);
}

// ===== RESUBMISSION of R6 (container-level failure, no test output; same
// failure signature as R0 which benched a known-good kernel => likely infra).
// Deadlock re-audit before resubmit: (1) all 10 waves run initial
// __syncthreads + exactly len s_barriers (computes/reader/scorer/idle each
// audited; no early return; len WG-uniform). (2) reader's iter-i poll
// terminates: computes issue iter-i adds BEFORE parking at barrier i.
// (3) LDS WAR: computes' ds_reads consumed (lgkmcnt) before barrier i;
// reader rewrites that parity only after barrier i+1. (4) no wave exits
// while any barrier remains. =====
//
// IC-gather RNN. grid=256 (1 WG/CU). XCD-local mapping: b=blk&31, q=blk>>5
// puts all 8 WGs of batch b at blk ≡ b (mod 8) -> same XCD under round-robin
// dispatch. Startup handshake VERIFIES this (correctness never assumes it):
// wave8 reads HW_REG_XCC_ID, adds 1<<(8*xcc) into gx[b], waits byte-sum==8;
// lok iff all 8 arrivals in its OWN byte. If lok: accumulator protocol runs
// with WORKGROUP-scope atomics at the shared XCD L2 (RT ~200cy vs LLC
// ~600cy). Fallback: agent scope (R3-verified).
// Per step i (h_i in LDS, guaranteed by the PER-STEP RAW BARRIER):
//   waves 0-7 (row r=w*64+lane): packed-FMA A = W_hh[r][own 64 cols]·h_i +
//     W_ih[r][own 16 cols]·x_i (x-part precomputed LAST iter, overlapping the
//     reader's poll), i32 fixed-point delta vs same-parity 2 steps ago, ONE
//     fire-and-forget atomic_add((1<<48)|delta) to slot[(i+1)&1][b][r]; then
//     next x-part; barrier.
//   wave 8 (prio 1): single-outstanding RMW(+0) poll until counter==8*uses
//     (R4: deeper polling delays producers' RMWs on the same lines), decode
//     (int32)low32, +bias, tanh, write LDS h[(i+1)&1], lgkmcnt(0), barrier.
//   wave 7 extra: publishes chunk-dot of h_i (tagged u64, agent scope) into
//     16-deep ring.
//   wave 9 q==0: NON-BLOCKING pipelined ring consume — checks LAST iter's
//     loads (full iter of flight ≫ LLC RT: never stalls the barrier),
//     consumes ≤1 step/iter, reissues, barriers; blocking drain post-loop.
//   wave 9 q!=0: barrier-idles len times (early return would hang the HW
//     barrier).
// Barrier-WAR safety: reader writes parity P at iter i; computes read P at
// iter i+1 (post-barrier-i); reader rewrites P at iter i+2, after barrier
// i+1, which requires computes' reads retired (data-dep before their add).
// Parity-slot reuse safe (read->barrier->compute->add causality). Carry-safe
// packing: low field = 2^46 + S*2^22, |S|<2^9.
__global__ __launch_bounds__(NTH, 1)
void rnn_seq(const float* __restrict__ x, const int* __restrict__ lengths,
             const float* __restrict__ W_ih, const float* __restrict__ W_hh,
             const float* __restrict__ b_ih, const float* __restrict__ b_hh,
             const float* __restrict__ W1, const float* __restrict__ b1,
             const float* __restrict__ W2, const float* __restrict__ b2,
             float* __restrict__ out, uint64_t* __restrict__ ws)
{
    const int blk  = blockIdx.x;
    const int b    = blk & 31;      // batch: all 8 WGs of b share blk%8 -> same XCD
    const int q    = blk >> 5;      // col-chunk owned by this WG
    const int tid  = threadIdx.x;
    const int w    = tid >> 6;
    const int lane = tid & 63;
    const int len  = lengths[b];

    uint64_t* gh  = ws;                         // [2][BB][HH] row accumulators
    uint64_t* gsd = ws + 2 * BB * HH;           // [BB][16][8] scorer ring
    uint64_t* gx  = gsd + BB * 16 * 8;          // [BB] xcd handshake

    __shared__ float hsh[2][64];                // h chunk, 2-parity
    __shared__ float biass[64];
    __shared__ int   lok_s;                     // 1 = all 8 WGs on this XCD

    if (w == 8) {
        biass[lane] = b_ih[q * 64 + lane] + b_hh[q * 64 + lane];
        hsh[0][lane] = 0.0f;                    // h_0 = 0
        uint32_t xcc_raw;
        asm volatile("s_getreg_b32 %0, hwreg(HW_REG_XCC_ID)" : "=s"(xcc_raw));
        const uint32_t xcc = xcc_raw & 7;
        if (lane == 0) {
            uint64_t* gxp = gx + b;
            __hip_atomic_fetch_add(gxp, 1ull << (8 * xcc),
                                   __ATOMIC_RELAXED, __HIP_MEMORY_SCOPE_AGENT);
            uint64_t v;
            do { v = gld_agent(gxp); }
            while ((uint8_t)((v * 0x0101010101010101ull) >> 56) != 8);
            lok_s = (v == (8ull << (8 * xcc))) ? 1 : 0;
        }
    }
    __syncthreads();
    const bool lok = (lok_s != 0);

    if (w < 8) {
        // ================= compute+add role: row r =================
        const int r = w * 64 + lane;
        float4 ww[16];
        { const float4* p = (const float4*)(W_hh + (size_t)r * HH + q * 64);
          #pragma unroll
          for (int k = 0; k < 16; ++k) ww[k] = p[k]; }
        float4 wi[4];
        { const float4* p = (const float4*)(W_ih + r * FF + q * 16);
          #pragma unroll
          for (int k = 0; k < 4; ++k) wi[k] = p[k]; }
        float wvreg = 0.0f;
        if (w == 7) {                           // scorer weight for col q*64+lane
            const int col = q * 64 + lane;
            #pragma unroll 8
            for (int f = 0; f < FCC; ++f) wvreg += W2[f] * W1[f * HH + col];
        }
        int prevI[2] = {0, 0};
        const float* xb = x + (size_t)b * TT * FF + q * 16;
        float4 xc[4], xn[4];
        { const float4* p = (const float4*)xb;
          #pragma unroll
          for (int k = 0; k < 4; ++k) xc[k] = p[k]; }
        { const float4* p = (const float4*)(xb + FF);
          #pragma unroll
          for (int k = 0; k < 4; ++k) xn[k] = p[k]; }

        uint64_t* ghb = gh + (size_t)b * HH + r;

        // x-part for i=0 (pre-loop; thereafter computed at end of prev iter)
        f32x2 acc01 = {0.0f, 0.0f};
        f32x2 acc23 = {0.0f, 0.0f};
        #pragma unroll
        for (int k = 0; k < 4; ++k) {
            pk_fma(acc01, lo2(wi[k]), lo2(xc[k]));
            pk_fma(acc23, hi2(wi[k]), hi2(xc[k]));
        }

        for (int i = 0; i < len; ++i) {
            // h_i ready in hsh[i&1] (initial sync / previous barrier)
            const float* hc = hsh[i & 1];
            const float4* hq = (const float4*)hc;
            #pragma unroll
            for (int k = 0; k < 16; ++k) {
                float4 hk = hq[k];
                pk_fma(acc01, lo2(ww[k]), lo2(hk));
                pk_fma(acc23, hi2(ww[k]), hi2(hk));
            }
            float A = (acc01.x + acc01.y) + (acc23.x + acc23.y);

            float hown = 0.0f;
            if (w == 7) hown = hc[lane];        // capture h_i for scorer dot

            int fi = __float2int_rn(A * SCALE_F);
            const int pn = (i + 1) & 1;
            long long con = (long long)CNT_ONE + (long long)(fi - prevI[pn])
                          + ((i < 2) ? BIAS_SHARE : 0);
            prevI[pn] = fi;
            uint64_t* slot = ghb + (size_t)pn * BB * HH;
            if (lok)                             // L2-local RMW (same-XCD verified)
                __hip_atomic_fetch_add(slot, (uint64_t)con,
                                       __ATOMIC_RELAXED, __HIP_MEMORY_SCOPE_WORKGROUP);
            else
                atomicAdd((unsigned long long*)slot, (unsigned long long)con);

            if (w == 7 && i > 0) {              // scorer chunk-dot of h_i
                float d = hown * wvreg;
                d += __shfl_xor(d, 1);  d += __shfl_xor(d, 2);
                d += __shfl_xor(d, 4);  d += __shfl_xor(d, 8);
                d += __shfl_xor(d, 16); d += __shfl_xor(d, 32);
                if (lane == 0) {
                    uint64_t pk = ((uint64_t)(uint32_t)i << 32) |
                                  (uint64_t)__float_as_uint(d);
                    __hip_atomic_store(&gsd[((size_t)b * 16 + (i & 15)) * 8 + q],
                                       pk, __ATOMIC_RELAXED, __HIP_MEMORY_SCOPE_AGENT);
                }
            }
            // ---- next-iter x prep + x-part: overlaps the reader's poll
            #pragma unroll
            for (int k = 0; k < 4; ++k) xc[k] = xn[k];
            if (i + 2 < len) {
                const float4* p = (const float4*)(xb + (size_t)(i + 2) * FF);
                #pragma unroll
                for (int k = 0; k < 4; ++k) xn[k] = p[k];
            }
            acc01.x = 0.0f; acc01.y = 0.0f;
            acc23.x = 0.0f; acc23.y = 0.0f;
            #pragma unroll
            for (int k = 0; k < 4; ++k) {
                pk_fma(acc01, lo2(wi[k]), lo2(xc[k]));
                pk_fma(acc23, hi2(wi[k]), hi2(xc[k]));
            }
            wg_barrier();
        }
        if (w == 7) {                            // final scorer dot: h_len
            // h_len visible: last barrier released after reader wrote it
            float d = hsh[len & 1][lane] * wvreg;
            d += __shfl_xor(d, 1);  d += __shfl_xor(d, 2);
            d += __shfl_xor(d, 4);  d += __shfl_xor(d, 8);
            d += __shfl_xor(d, 16); d += __shfl_xor(d, 32);
            if (lane == 0) {
                uint64_t pk = ((uint64_t)(uint32_t)len << 32) |
                              (uint64_t)__float_as_uint(d);
                __hip_atomic_store(&gsd[((size_t)b * 16 + (len & 15)) * 8 + q],
                                   pk, __ATOMIC_RELAXED, __HIP_MEMORY_SCOPE_AGENT);
            }
        }
    } else if (w == 8) {
        // ================= reader role: own 64 slots =================
        __builtin_amdgcn_s_setprio(1);          // win SIMD arbitration
        uint64_t z = 0;
        asm("" : "+v"(z));                      // opaque zero: keeps fetch_add a real RMW
        float hval = 0.0f;
        for (int i = 0; i < len; ++i) {
            const int j  = i + 1;
            const int pn = j & 1;
            const uint64_t target = 8ull * (uint64_t)((j + 1) >> 1); // 8*uses of this parity
            uint64_t* pr = gh + (size_t)pn * BB * HH + (size_t)b * HH + q * 64 + lane;
            uint64_t u;
            if (lok) {
                // workgroup-scope RMW(+0): executes at the XCD L2 (atomics
                // bypass L1), returns the fresh value. Single-outstanding.
                do { u = __hip_atomic_fetch_add(pr, z, __ATOMIC_RELAXED,
                                                __HIP_MEMORY_SCOPE_WORKGROUP); }
                while ((u >> 48) != target);
            } else {
                do { u = gld_agent(pr); } while ((u >> 48) != target);
            }
            // i32 decode: 2^46/2^43 bias ≡ 0 mod 2^32, |S·2^22| < 2^31
            float pre = (float)(int)(uint32_t)u * INV_SCALE_F + biass[lane];
            hval = fast_tanh(pre);
            hsh[pn][lane] = hval;
            wait_lgkm0();                       // h write visible before release
            wg_barrier();
        }
        out[BB + b * HH + q * 64 + lane] = hval;   // h_final chunk
    } else if (q == 0) {
        // ========== scorer (q==0): non-blocking pipelined consume ==========
        float cconst = b2[0];
        for (int f = 0; f < FCC; ++f) cconst += W2[f] * b1[f];
        int count = 0;
        int jn = 1;
        uint64_t upend = 0;                     // tag 0 never matches jn>=1
        for (int i = 0; i < len; ++i) {
            // check LAST iter's loads (full iter of flight ≫ LLC RT)
            bool ok = (lane < 8) ? ((int)(upend >> 32) == jn) : true;
            if (__all(ok)) {
                float d = (lane < 8) ? __uint_as_float((uint32_t)upend) : 0.0f;
                d += __shfl_xor(d, 1); d += __shfl_xor(d, 2); d += __shfl_xor(d, 4);
                if (lane == 0 && d + cconst > 0.0f) ++count;
                ++jn;
            }
            // reissue for (possibly advanced) jn — checked next iter
            upend = (lane < 8)
                  ? gld_agent(gsd + ((size_t)b * 16 + (jn & 15)) * 8 + lane)
                  : 0ull;
            wg_barrier();
        }
        // drain the tail (blocking; producers' final publishes in flight)
        while (jn <= len) {
            float d = 0.0f;
            if (lane < 8) {
                uint64_t* pr = gsd + ((size_t)b * 16 + (jn & 15)) * 8 + lane;
                uint64_t u;
                do { u = gld_agent(pr); } while ((int)(u >> 32) != jn);
                d = __uint_as_float((uint32_t)u);
            }
            d += __shfl_xor(d, 1); d += __shfl_xor(d, 2); d += __shfl_xor(d, 4);
            if (lane == 0 && d + cconst > 0.0f) ++count;
            ++jn;
        }
        if (lane == 0) out[b] = (float)count;
    } else {
        // ====== wave 9, q!=0: barrier-idle (early return would hang) ======
        for (int i = 0; i < len; ++i) wg_barrier();
    }
}

extern "C" void kernel_launch(void* const* d_in, const int* in_sizes, int n_in,
                              void* d_out, int out_size, void* d_ws, size_t ws_size,
                              hipStream_t stream) {
    const float* x    = (const float*)d_in[0];
    const int*   lens = (const int*)d_in[1];
    const float* W_ih = (const float*)d_in[2];
    const float* W_hh = (const float*)d_in[3];
    const float* b_ih = (const float*)d_in[4];
    const float* b_hh = (const float*)d_in[5];
    const float* W1   = (const float*)d_in[6];
    const float* b1   = (const float*)d_in[7];
    const float* W2   = (const float*)d_in[8];
    const float* b2   = (const float*)d_in[9];
    float* out = (float*)d_out;
    uint64_t* ws = (uint64_t*)d_ws;   // WS_U64 u64 = 295168 B

    ws_zero<<<dim3(145), dim3(256), 0, stream>>>(ws);
    rnn_seq<<<dim3(BB * QW), dim3(NTH), 0, stream>>>(
        x, lens, W_ih, W_hh, b_ih, b_hh, W1, b1, W2, b2, out, ws);
}

// Round 8
// 2575.226 us; speedup vs baseline: 1.2319x; 1.0352x over previous
//
#include <hip/hip_runtime.h>
#include <math.h>
#include <stdint.h>

#define BB 32
#define TT 2048
#define FF 128
#define HH 512
#define FCC 128
#define QW 8
#define NTH 640   // 10 waves: 0-7 compute+add, 8 reader, 9 scorer (q==0) / barrier-idle

#define SCALE_F     4194304.0f             // 2^22 fixed-point scale (i32-decodable)
#define INV_SCALE_F (1.0f/4194304.0f)
#define CNT_ONE     (1ull<<48)             // arrival counter increment
#define BIAS_TOTAL  (1ll<<46)              // keeps low field positive: no carry into bit 48
#define BIAS_SHARE  (1ll<<43)              // BIAS_TOTAL / 8 (one share per WG, first use of each parity)
// 2^46 and 2^43 are both ≡ 0 mod 2^32, and |A·2^22| < 2^31, so the reader
// decodes the signed sum as (int32)(low 32 bits) — no 64-bit ops needed.

#define WS_U64 (2*BB*HH + BB*16*8 + BB)    // gh + gsd + gx handshake

typedef float f32x2 __attribute__((ext_vector_type(2)));

__global__ void ws_zero(uint64_t* g) {     // counters/tags must start at 0 (0xAA poison aliases)
    size_t i = (size_t)blockIdx.x * blockDim.x + threadIdx.x;
    if (i < WS_U64) g[i] = 0ull;
}

__device__ __forceinline__ void wait_lgkm0() {
    asm volatile("s_waitcnt lgkmcnt(0)" ::: "memory");
}

// raw WG barrier: NO implicit vmcnt drain (fire-and-forget adds stay in
// flight). Compile-level memory fences on both sides so LDS ops can't be
// scheduled across it.
__device__ __forceinline__ void wg_barrier() {
    asm volatile("" ::: "memory");
    __builtin_amdgcn_s_barrier();
    asm volatile("" ::: "memory");
}

__device__ __forceinline__ float fast_tanh(float z) {
    float ax = fabsf(z);
    float e  = __expf(-2.0f * ax);
    float r  = (1.0f - e) / (1.0f + e);
    return copysignf(r, z);
}

// packed f32 FMA: d.lo += a.lo*b.lo, d.hi += a.hi*b.hi  (full-rate on CDNA4)
__device__ __forceinline__ void pk_fma(f32x2& d, f32x2 a, f32x2 b) {
    asm("v_pk_fma_f32 %0, %1, %2, %0" : "+v"(d) : "v"(a), "v"(b));
}
__device__ __forceinline__ f32x2 lo2(float4 v) { f32x2 r; r.x = v.x; r.y = v.y; return r; }
__device__ __forceinline__ f32x2 hi2(float4 v) { f32x2 r; r.x = v.z; r.y = v.w; return r; }

__device__ __forceinline__ uint64_t gld_agent(const uint64_t* p) {
    return __hip_atomic_load(p, __ATOMIC_RELAXED, __HIP_MEMORY_SCOPE_AGENT);
}

// IC-gather RNN. grid=256 (1 WG/CU). XCD-local mapping: b=blk&31, q=blk>>5
// puts all 8 WGs of batch b at blk ≡ b (mod 8) -> same XCD under round-robin
// dispatch. Startup handshake VERIFIES this (correctness never assumes it):
// wave8 reads HW_REG_XCC_ID, adds 1<<(8*xcc) into gx[b], waits byte-sum==8;
// lok iff all 8 arrivals in its OWN byte. If lok: accumulator protocol runs
// with WORKGROUP-scope atomics at the shared XCD L2 (RT ~200cy vs LLC
// ~600cy). Fallback: agent scope (R3-verified).
// Per step i (h_i in LDS, guaranteed by the PER-STEP RAW BARRIER):
//   waves 0-7 (row r=w*64+lane): packed-FMA A = W_hh[r][own 64 cols]·h_i +
//     W_ih[r][own 16 cols]·x_i (x-part precomputed LAST iter; 4 independent
//     FMA chains, dep depth 8), i32 fixed-point delta vs same-parity 2 steps
//     ago, ONE fire-and-forget atomic_add((1<<48)|delta) to
//     slot[(i+1)&1][b][r]; then next x-part; barrier.
//   wave 8 (prio 1): CROSS-STEP PIPELINED poll — after detecting step j,
//     issues ONE plain agent-load prefetch of step j+1's slot; its flight
//     overlaps tanh+barrier+MAC (~300cy). Next step's poll is seeded with
//     the prefetched value; stale/incomplete tag -> falls through to the
//     verified single-outstanding RMW(+0) poll (R4: same-step deep polling
//     delays producers' RMWs; one cross-step load does not). Overshoot
//     impossible (counter monotone, ==target only when all 8 adds applied).
//     Decode (int32)low32, +bias, tanh, write LDS h[(i+1)&1], lgkmcnt(0),
//     barrier.
//   wave 7 extra: publishes chunk-dot of h_i (tagged u64, agent scope) into
//     16-deep ring.
//   wave 9 q==0: NON-BLOCKING pipelined ring consume — checks LAST iter's
//     loads, consumes ≤1 step/iter, reissues, barriers; blocking drain
//     post-loop.  wave 9 q!=0: barrier-idles len times.
// Barrier-WAR safety: reader writes parity P at iter i; computes read P at
// iter i+1 (post-barrier-i); reader rewrites P at iter i+2, after barrier
// i+1, which requires computes' reads retired (data-dep before their add).
// Every wave executes exactly len barriers + initial __syncthreads.
// Parity-slot reuse safe (read->barrier->compute->add causality). Carry-safe
// packing: low field = 2^46 + S*2^22, |S|<2^9.
__global__ __launch_bounds__(NTH, 1)
void rnn_seq(const float* __restrict__ x, const int* __restrict__ lengths,
             const float* __restrict__ W_ih, const float* __restrict__ W_hh,
             const float* __restrict__ b_ih, const float* __restrict__ b_hh,
             const float* __restrict__ W1, const float* __restrict__ b1,
             const float* __restrict__ W2, const float* __restrict__ b2,
             float* __restrict__ out, uint64_t* __restrict__ ws)
{
    const int blk  = blockIdx.x;
    const int b    = blk & 31;      // batch: all 8 WGs of b share blk%8 -> same XCD
    const int q    = blk >> 5;      // col-chunk owned by this WG
    const int tid  = threadIdx.x;
    const int w    = tid >> 6;
    const int lane = tid & 63;
    const int len  = lengths[b];

    uint64_t* gh  = ws;                         // [2][BB][HH] row accumulators
    uint64_t* gsd = ws + 2 * BB * HH;           // [BB][16][8] scorer ring
    uint64_t* gx  = gsd + BB * 16 * 8;          // [BB] xcd handshake

    __shared__ float hsh[2][64];                // h chunk, 2-parity
    __shared__ float biass[64];
    __shared__ int   lok_s;                     // 1 = all 8 WGs on this XCD

    if (w == 8) {
        biass[lane] = b_ih[q * 64 + lane] + b_hh[q * 64 + lane];
        hsh[0][lane] = 0.0f;                    // h_0 = 0
        uint32_t xcc_raw;
        asm volatile("s_getreg_b32 %0, hwreg(HW_REG_XCC_ID)" : "=s"(xcc_raw));
        const uint32_t xcc = xcc_raw & 7;
        if (lane == 0) {
            uint64_t* gxp = gx + b;
            __hip_atomic_fetch_add(gxp, 1ull << (8 * xcc),
                                   __ATOMIC_RELAXED, __HIP_MEMORY_SCOPE_AGENT);
            uint64_t v;
            do { v = gld_agent(gxp); }
            while ((uint8_t)((v * 0x0101010101010101ull) >> 56) != 8);
            lok_s = (v == (8ull << (8 * xcc))) ? 1 : 0;
        }
    }
    __syncthreads();
    const bool lok = (lok_s != 0);

    if (w < 8) {
        // ================= compute+add role: row r =================
        const int r = w * 64 + lane;
        float4 ww[16];
        { const float4* p = (const float4*)(W_hh + (size_t)r * HH + q * 64);
          #pragma unroll
          for (int k = 0; k < 16; ++k) ww[k] = p[k]; }
        float4 wi[4];
        { const float4* p = (const float4*)(W_ih + r * FF + q * 16);
          #pragma unroll
          for (int k = 0; k < 4; ++k) wi[k] = p[k]; }
        float wvreg = 0.0f;
        if (w == 7) {                           // scorer weight for col q*64+lane
            const int col = q * 64 + lane;
            #pragma unroll 8
            for (int f = 0; f < FCC; ++f) wvreg += W2[f] * W1[f * HH + col];
        }
        int prevI[2] = {0, 0};
        const float* xb = x + (size_t)b * TT * FF + q * 16;
        float4 xc[4], xn[4];
        { const float4* p = (const float4*)xb;
          #pragma unroll
          for (int k = 0; k < 4; ++k) xc[k] = p[k]; }
        { const float4* p = (const float4*)(xb + FF);
          #pragma unroll
          for (int k = 0; k < 4; ++k) xn[k] = p[k]; }

        uint64_t* ghb = gh + (size_t)b * HH + r;

        // x-part for i=0 (pre-loop; thereafter computed at end of prev iter)
        // 4 independent accumulator chains (a0..a3); x-part feeds a0/a1.
        f32x2 a0 = {0.0f, 0.0f}, a1 = {0.0f, 0.0f};
        f32x2 a2 = {0.0f, 0.0f}, a3 = {0.0f, 0.0f};
        #pragma unroll
        for (int k = 0; k < 4; ++k) {
            pk_fma(a0, lo2(wi[k]), lo2(xc[k]));
            pk_fma(a1, hi2(wi[k]), hi2(xc[k]));
        }

        for (int i = 0; i < len; ++i) {
            // h_i ready in hsh[i&1] (initial sync / previous barrier)
            const float* hc = hsh[i & 1];
            const float4* hq = (const float4*)hc;
            #pragma unroll
            for (int k = 0; k < 16; k += 2) {
                float4 hk0 = hq[k];
                float4 hk1 = hq[k + 1];
                pk_fma(a0, lo2(ww[k]),     lo2(hk0));
                pk_fma(a1, hi2(ww[k]),     hi2(hk0));
                pk_fma(a2, lo2(ww[k + 1]), lo2(hk1));
                pk_fma(a3, hi2(ww[k + 1]), hi2(hk1));
            }
            float A = ((a0.x + a0.y) + (a1.x + a1.y))
                    + ((a2.x + a2.y) + (a3.x + a3.y));

            float hown = 0.0f;
            if (w == 7) hown = hc[lane];        // capture h_i for scorer dot

            int fi = __float2int_rn(A * SCALE_F);
            const int pn = (i + 1) & 1;
            long long con = (long long)CNT_ONE + (long long)(fi - prevI[pn])
                          + ((i < 2) ? BIAS_SHARE : 0);
            prevI[pn] = fi;
            uint64_t* slot = ghb + (size_t)pn * BB * HH;
            if (lok)                             // L2-local RMW (same-XCD verified)
                __hip_atomic_fetch_add(slot, (uint64_t)con,
                                       __ATOMIC_RELAXED, __HIP_MEMORY_SCOPE_WORKGROUP);
            else
                atomicAdd((unsigned long long*)slot, (unsigned long long)con);

            if (w == 7 && i > 0) {              // scorer chunk-dot of h_i
                float d = hown * wvreg;
                d += __shfl_xor(d, 1);  d += __shfl_xor(d, 2);
                d += __shfl_xor(d, 4);  d += __shfl_xor(d, 8);
                d += __shfl_xor(d, 16); d += __shfl_xor(d, 32);
                if (lane == 0) {
                    uint64_t pk = ((uint64_t)(uint32_t)i << 32) |
                                  (uint64_t)__float_as_uint(d);
                    __hip_atomic_store(&gsd[((size_t)b * 16 + (i & 15)) * 8 + q],
                                       pk, __ATOMIC_RELAXED, __HIP_MEMORY_SCOPE_AGENT);
                }
            }
            // ---- next-iter x prep + x-part: overlaps the reader's poll
            #pragma unroll
            for (int k = 0; k < 4; ++k) xc[k] = xn[k];
            if (i + 2 < len) {
                const float4* p = (const float4*)(xb + (size_t)(i + 2) * FF);
                #pragma unroll
                for (int k = 0; k < 4; ++k) xn[k] = p[k];
            }
            a0.x = 0.0f; a0.y = 0.0f; a1.x = 0.0f; a1.y = 0.0f;
            a2.x = 0.0f; a2.y = 0.0f; a3.x = 0.0f; a3.y = 0.0f;
            #pragma unroll
            for (int k = 0; k < 4; ++k) {
                pk_fma(a0, lo2(wi[k]), lo2(xc[k]));
                pk_fma(a1, hi2(wi[k]), hi2(xc[k]));
            }
            wg_barrier();
        }
        if (w == 7) {                            // final scorer dot: h_len
            // h_len visible: last barrier released after reader wrote it
            float d = hsh[len & 1][lane] * wvreg;
            d += __shfl_xor(d, 1);  d += __shfl_xor(d, 2);
            d += __shfl_xor(d, 4);  d += __shfl_xor(d, 8);
            d += __shfl_xor(d, 16); d += __shfl_xor(d, 32);
            if (lane == 0) {
                uint64_t pk = ((uint64_t)(uint32_t)len << 32) |
                              (uint64_t)__float_as_uint(d);
                __hip_atomic_store(&gsd[((size_t)b * 16 + (len & 15)) * 8 + q],
                                   pk, __ATOMIC_RELAXED, __HIP_MEMORY_SCOPE_AGENT);
            }
        }
    } else if (w == 8) {
        // ================= reader role: own 64 slots =================
        __builtin_amdgcn_s_setprio(1);          // win SIMD arbitration
        uint64_t z = 0;
        asm("" : "+v"(z));                      // opaque zero: keeps fetch_add a real RMW
        float hval = 0.0f;
        uint64_t upre = 0;                      // cross-step prefetch (tag 0 < any target)
        for (int i = 0; i < len; ++i) {
            const int j  = i + 1;
            const int pn = j & 1;
            const uint64_t target = 8ull * (uint64_t)((j + 1) >> 1); // 8*uses of this parity
            uint64_t* pr = gh + (size_t)pn * BB * HH + (size_t)b * HH + q * 64 + lane;
            // seed with last step's prefetch; verified single-outstanding
            // RMW(+0) poll as fallback (executes at XCD L2, bypasses L1).
            uint64_t u = upre;
            if (lok) {
                while ((u >> 48) != target)
                    u = __hip_atomic_fetch_add(pr, z, __ATOMIC_RELAXED,
                                               __HIP_MEMORY_SCOPE_WORKGROUP);
            } else {
                while ((u >> 48) != target)
                    u = gld_agent(pr);
            }
            // issue ONE prefetch for step j+1 (other parity); flight overlaps
            // tanh+barrier+MAC. Plain load: no atomic-unit occupancy; stale
            // or incomplete -> next loop falls through to the RMW poll.
            if (i + 1 < len) {
                uint64_t* prn = gh + (size_t)((j + 1) & 1) * BB * HH
                              + (size_t)b * HH + q * 64 + lane;
                upre = gld_agent(prn);
            }
            // i32 decode: 2^46/2^43 bias ≡ 0 mod 2^32, |S·2^22| < 2^31
            float pre = (float)(int)(uint32_t)u * INV_SCALE_F + biass[lane];
            hval = fast_tanh(pre);
            hsh[pn][lane] = hval;
            wait_lgkm0();                       // h write visible before release
            wg_barrier();
        }
        out[BB + b * HH + q * 64 + lane] = hval;   // h_final chunk
    } else if (q == 0) {
        // ========== scorer (q==0): non-blocking pipelined consume ==========
        float cconst = b2[0];
        for (int f = 0; f < FCC; ++f) cconst += W2[f] * b1[f];
        int count = 0;
        int jn = 1;
        uint64_t upend = 0;                     // tag 0 never matches jn>=1
        for (int i = 0; i < len; ++i) {
            // check LAST iter's loads (full iter of flight ≫ LLC RT)
            bool ok = (lane < 8) ? ((int)(upend >> 32) == jn) : true;
            if (__all(ok)) {
                float d = (lane < 8) ? __uint_as_float((uint32_t)upend) : 0.0f;
                d += __shfl_xor(d, 1); d += __shfl_xor(d, 2); d += __shfl_xor(d, 4);
                if (lane == 0 && d + cconst > 0.0f) ++count;
                ++jn;
            }
            // reissue for (possibly advanced) jn — checked next iter
            upend = (lane < 8)
                  ? gld_agent(gsd + ((size_t)b * 16 + (jn & 15)) * 8 + lane)
                  : 0ull;
            wg_barrier();
        }
        // drain the tail (blocking; producers' final publishes in flight)
        while (jn <= len) {
            float d = 0.0f;
            if (lane < 8) {
                uint64_t* pr = gsd + ((size_t)b * 16 + (jn & 15)) * 8 + lane;
                uint64_t u;
                do { u = gld_agent(pr); } while ((int)(u >> 32) != jn);
                d = __uint_as_float((uint32_t)u);
            }
            d += __shfl_xor(d, 1); d += __shfl_xor(d, 2); d += __shfl_xor(d, 4);
            if (lane == 0 && d + cconst > 0.0f) ++count;
            ++jn;
        }
        if (lane == 0) out[b] = (float)count;
    } else {
        // ====== wave 9, q!=0: barrier-idle (early return would hang) ======
        for (int i = 0; i < len; ++i) wg_barrier();
    }
}

extern "C" void kernel_launch(void* const* d_in, const int* in_sizes, int n_in,
                              void* d_out, int out_size, void* d_ws, size_t ws_size,
                              hipStream_t stream) {
    const float* x    = (const float*)d_in[0];
    const int*   lens = (const int*)d_in[1];
    const float* W_ih = (const float*)d_in[2];
    const float* W_hh = (const float*)d_in[3];
    const float* b_ih = (const float*)d_in[4];
    const float* b_hh = (const float*)d_in[5];
    const float* W1   = (const float*)d_in[6];
    const float* b1   = (const float*)d_in[7];
    const float* W2   = (const float*)d_in[8];
    const float* b2   = (const float*)d_in[9];
    float* out = (float*)d_out;
    uint64_t* ws = (uint64_t*)d_ws;   // WS_U64 u64 = 295168 B

    ws_zero<<<dim3(145), dim3(256), 0, stream>>>(ws);
    rnn_seq<<<dim3(BB * QW), dim3(NTH), 0, stream>>>(
        x, lens, W_ih, W_hh, b_ih, b_hh, W1, b1, W2, b2, out, ws);
}